// Round 1
// baseline (106.230 us; speedup 1.0000x reference)
//
#include <hip/hip_runtime.h>
#include <stdint.h>

#define BATCH 8
#define SEQ   2048
#define EMB   1024
#define HD    128

typedef __attribute__((ext_vector_type(8))) short  s8v;
typedef __attribute__((ext_vector_type(4))) float  f4v;

__device__ __forceinline__ ushort cvt_bf16(float f) {
    union { float f; uint32_t u; } v; v.f = f;
    uint32_t r = v.u + 0x7FFFu + ((v.u >> 16) & 1u);
    return (ushort)(r >> 16);
}

__device__ __forceinline__ f4v mfma16(s8v a, s8v b, f4v c) {
    return __builtin_amdgcn_mfma_f32_16x16x32_bf16(a, b, c, 0, 0, 0);
}

// ---------------- Stage 1: fused QKV projection (NT GEMM, f32 in, bf16 out) --------
// grid = (128 M-tiles, 3 weights). Tile 128x128, BK=64, 4 waves (2x2 of 64x64).
__global__ __launch_bounds__(256) void qkv_kernel(
    const float* __restrict__ x,
    const float* __restrict__ Wk,
    const float* __restrict__ Wq,
    const float* __restrict__ Wv,
    ushort* __restrict__ Kg,     // [B*T][128] bf16
    ushort* __restrict__ Qg,     // [B*T][128] bf16
    ushort* __restrict__ VTg)    // [B][128][T] bf16 (transposed)
{
    const int mt   = blockIdx.x;   // 0..127
    const int wsel = blockIdx.y;   // 0:K 1:Q 2:V
    const float* __restrict__ W = (wsel == 0) ? Wk : (wsel == 1) ? Wq : Wv;
    const int m0 = mt * 128;

    __shared__ ushort Al[128][72];   // 64 cols + 8 pad (stride 144B = 36 dw -> 2-way)
    __shared__ ushort Bl[128][72];

    const int tid  = threadIdx.x;
    const int lane = tid & 63;
    const int wave = tid >> 6;
    const int wm = wave >> 1, wn = wave & 1;
    const int lr = lane & 15, lg = lane >> 4;

    f4v acc[4][4] = {};

    for (int k0 = 0; k0 < EMB; k0 += 64) {
        #pragma unroll
        for (int it = 0; it < 8; ++it) {
            int chunk = tid + 256 * it;          // 2048 chunks of 4 f32
            int r  = chunk >> 4;
            int c4 = (chunk & 15) << 2;
            float4 fa = *(const float4*)(x + (size_t)(m0 + r) * EMB + k0 + c4);
            ushort4 ha;
            ha.x = cvt_bf16(fa.x); ha.y = cvt_bf16(fa.y);
            ha.z = cvt_bf16(fa.z); ha.w = cvt_bf16(fa.w);
            *(ushort4*)&Al[r][c4] = ha;
            float4 fb = *(const float4*)(W + (size_t)r * EMB + k0 + c4);
            ushort4 hb;
            hb.x = cvt_bf16(fb.x); hb.y = cvt_bf16(fb.y);
            hb.z = cvt_bf16(fb.z); hb.w = cvt_bf16(fb.w);
            *(ushort4*)&Bl[r][c4] = hb;
        }
        __syncthreads();
        #pragma unroll
        for (int kk = 0; kk < 2; ++kk) {
            s8v af[4], bf[4];
            #pragma unroll
            for (int i = 0; i < 4; ++i)
                af[i] = *(const s8v*)&Al[64 * wm + 16 * i + lr][32 * kk + 8 * lg];
            #pragma unroll
            for (int j = 0; j < 4; ++j)
                bf[j] = *(const s8v*)&Bl[64 * wn + 16 * j + lr][32 * kk + 8 * lg];
            #pragma unroll
            for (int i = 0; i < 4; ++i)
                #pragma unroll
                for (int j = 0; j < 4; ++j)
                    acc[i][j] = mfma16(af[i], bf[j], acc[i][j]);
        }
        __syncthreads();
    }

    if (wsel < 2) {
        ushort* __restrict__ outp = (wsel == 0) ? Kg : Qg;
        #pragma unroll
        for (int i = 0; i < 4; ++i)
            #pragma unroll
            for (int j = 0; j < 4; ++j) {
                int h = 64 * wn + 16 * j + lr;
                #pragma unroll
                for (int reg = 0; reg < 4; ++reg) {
                    int m = m0 + 64 * wm + 16 * i + 4 * lg + reg;
                    outp[(size_t)m * HD + h] = cvt_bf16(acc[i][j][reg]);
                }
            }
    } else {
        // V^T: lane's 4 regs are 4 consecutive t at fixed h -> one ushort4 store
        int bidx = m0 / SEQ;
        int tb   = m0 - bidx * SEQ;
        #pragma unroll
        for (int i = 0; i < 4; ++i)
            #pragma unroll
            for (int j = 0; j < 4; ++j) {
                int h = 64 * wn + 16 * j + lr;
                int t = tb + 64 * wm + 16 * i + 4 * lg;
                ushort4 hv;
                hv.x = cvt_bf16(acc[i][j][0]);
                hv.y = cvt_bf16(acc[i][j][1]);
                hv.z = cvt_bf16(acc[i][j][2]);
                hv.w = cvt_bf16(acc[i][j][3]);
                *(ushort4*)(VTg + ((size_t)bidx * HD + h) * SEQ + t) = hv;
            }
    }
}

// ---------------- Stage 2: causal flash attention ----------------------------------
// grid = 256 (8 batches x 32 q-blocks of 64 rows). 4 waves, 16 q-rows each.
__global__ __launch_bounds__(256) void attn_kernel(
    const ushort* __restrict__ Qg,
    const ushort* __restrict__ Kg,
    const ushort* __restrict__ VTg,
    float* __restrict__ out)
{
    const int b  = blockIdx.x >> 5;
    const int jq = blockIdx.x & 31;
    const int tid  = threadIdx.x;
    const int lane = tid & 63;
    const int wave = tid >> 6;
    const int lr = lane & 15, lg = lane >> 4;

    __shared__ ushort kl[64][136];    // K tile [s][k], +8 pad
    __shared__ ushort vl[128][72];    // V^T tile [h][s], +8 pad
    __shared__ ushort pl[4][16][72];  // per-wave P tile [q][s], +8 pad

    const int qw = jq * 64 + wave * 16;    // wave's q-row base (within batch)
    const ushort* __restrict__ Qb = Qg  + (size_t)b * SEQ * HD;
    const ushort* __restrict__ Kb = Kg  + (size_t)b * SEQ * HD;
    const ushort* __restrict__ Vb = VTg + (size_t)b * HD * SEQ;

    s8v qf[4];
    #pragma unroll
    for (int f = 0; f < 4; ++f)
        qf[f] = *(const s8v*)(Qb + (size_t)(qw + lr) * HD + 32 * f + 8 * lg);

    f4v o[8] = {};
    float m_r[4], l_r[4];
    #pragma unroll
    for (int r = 0; r < 4; ++r) { m_r[r] = -1e30f; l_r[r] = 0.0f; }

    for (int st = 0; st <= jq; ++st) {
        const int s0 = st * 64;
        #pragma unroll
        for (int it = 0; it < 4; ++it) {
            int chunk = tid + 256 * it;                 // 1024 chunks of 16B
            int r  = chunk >> 4, c8 = (chunk & 15) << 3;
            *(int4*)&kl[r][c8] = *(const int4*)(Kb + (size_t)(s0 + r) * HD + c8);
            int rh = chunk >> 3, cs = (chunk & 7) << 3;
            *(int4*)&vl[rh][cs] = *(const int4*)(Vb + (size_t)rh * SEQ + s0 + cs);
        }
        __syncthreads();

        // QK^T: S[16q x 64s]
        f4v sc[4] = {};
        #pragma unroll
        for (int sf = 0; sf < 4; ++sf)
            #pragma unroll
            for (int kf = 0; kf < 4; ++kf) {
                s8v kfr = *(const s8v*)&kl[sf * 16 + lr][kf * 32 + 8 * lg];
                sc[sf] = mfma16(qf[kf], kfr, sc[sf]);
            }

        // scale + causal mask (diagonal tile only)
        float p[4][4];
        const bool diag = (st == jq);
        #pragma unroll
        for (int sf = 0; sf < 4; ++sf)
            #pragma unroll
            for (int reg = 0; reg < 4; ++reg) {
                float v = sc[sf][reg] * 0.03125f;    // C^-0.5 = 1/32
                if (diag) {
                    int qrow = qw + 4 * lg + reg;
                    int srow = s0 + sf * 16 + lr;
                    if (srow > qrow) v = -1e30f;
                }
                p[sf][reg] = v;
            }

        // online softmax: rows are owned by 16-lane groups
        float fac[4];
        #pragma unroll
        for (int reg = 0; reg < 4; ++reg) {
            float v = fmaxf(fmaxf(p[0][reg], p[1][reg]), fmaxf(p[2][reg], p[3][reg]));
            v = fmaxf(v, __shfl_xor(v, 1));
            v = fmaxf(v, __shfl_xor(v, 2));
            v = fmaxf(v, __shfl_xor(v, 4));
            v = fmaxf(v, __shfl_xor(v, 8));
            float nm = fmaxf(m_r[reg], v);
            fac[reg] = __expf(m_r[reg] - nm);
            m_r[reg] = nm;
        }
        #pragma unroll
        for (int sf = 0; sf < 4; ++sf)
            #pragma unroll
            for (int reg = 0; reg < 4; ++reg)
                p[sf][reg] = __expf(p[sf][reg] - m_r[reg]);
        #pragma unroll
        for (int reg = 0; reg < 4; ++reg) {
            float v = p[0][reg] + p[1][reg] + p[2][reg] + p[3][reg];
            v += __shfl_xor(v, 1);
            v += __shfl_xor(v, 2);
            v += __shfl_xor(v, 4);
            v += __shfl_xor(v, 8);
            l_r[reg] = l_r[reg] * fac[reg] + v;
        }
        #pragma unroll
        for (int hf = 0; hf < 8; ++hf)
            #pragma unroll
            for (int reg = 0; reg < 4; ++reg)
                o[hf][reg] *= fac[reg];

        // P (D-layout) -> LDS bf16 -> A-fragment layout
        #pragma unroll
        for (int sf = 0; sf < 4; ++sf)
            #pragma unroll
            for (int reg = 0; reg < 4; ++reg)
                pl[wave][4 * lg + reg][sf * 16 + lr] = cvt_bf16(p[sf][reg]);
        __syncthreads();

        // PV: O[16q x 128h] += P[16q x 64s] * V[64s x 128h]
        #pragma unroll
        for (int s2 = 0; s2 < 2; ++s2) {
            s8v pa = *(const s8v*)&pl[wave][lr][s2 * 32 + 8 * lg];
            #pragma unroll
            for (int hf = 0; hf < 8; ++hf) {
                s8v vb = *(const s8v*)&vl[hf * 16 + lr][s2 * 32 + 8 * lg];
                o[hf] = mfma16(pa, vb, o[hf]);
            }
        }
        __syncthreads();
    }

    float inv[4];
    #pragma unroll
    for (int reg = 0; reg < 4; ++reg) inv[reg] = 1.0f / l_r[reg];
    #pragma unroll
    for (int hf = 0; hf < 8; ++hf)
        #pragma unroll
        for (int reg = 0; reg < 4; ++reg) {
            int q = qw + 4 * lg + reg;
            int h = hf * 16 + lr;
            out[((size_t)b * SEQ + q) * HD + h] = o[hf][reg] * inv[reg];
        }
}

extern "C" void kernel_launch(void* const* d_in, const int* in_sizes, int n_in,
                              void* d_out, int out_size, void* d_ws, size_t ws_size,
                              hipStream_t stream) {
    const float* x  = (const float*)d_in[0];
    const float* Wk = (const float*)d_in[1];
    const float* Wq = (const float*)d_in[2];
    const float* Wv = (const float*)d_in[3];

    ushort* Kg  = (ushort*)d_ws;                       // 4 MB
    ushort* Qg  = Kg + (size_t)BATCH * SEQ * HD;       // 4 MB
    ushort* VTg = Qg + (size_t)BATCH * SEQ * HD;       // 4 MB
    float*  outp = (float*)d_out;

    dim3 g1(128, 3);
    qkv_kernel<<<g1, 256, 0, stream>>>(x, Wk, Wq, Wv, Kg, Qg, VTg);
    attn_kernel<<<256, 256, 0, stream>>>(Qg, Kg, VTg, outp);
}